// Round 8
// baseline (241.156 us; speedup 1.0000x reference)
//
#include <hip/hip_runtime.h>

// MI355X / gfx950. bf16 MFMA BERT attention with relu^2 "softmax".
// R14: (a) attn reverted to R12 exactly (87us measured; R13's 4-block
// variant regressed to 91 -- barrier-group topology was not the limiter).
// (b) qkv restructured BK=64 -> BK=32 double-buffer: LDS 64KB -> 32KB ->
// 4 blocks/CU (was 2), __launch_bounds__(256,4). Same single-barrier
// pipeline { stage(s+1); 16 MFMA; vmcnt(0); barrier }, 32 steps. The 2x
// resident blocks hide the staging latency the thin compute exposes.
// BK=32 swizzle (verified in R9): store chunk ch at ch^((row>>1)&3);
// frag-read chunk = quad^((l16>>1)&3) -> 2-way bank alias = free.
// 32x32 layouts (HW-verified C/D):
//   A: lane l holds A[m=l&31][k=(l>>5)*8+j]
//   B: lane l holds B[k=(l>>5)*8+j][n=l&31]
//   C/D: lane l reg r holds D[row=(r&3)+8*(r>>2)+4*(l>>5)][col=l&31]

typedef __bf16 bf16x8 __attribute__((ext_vector_type(8)));
typedef __bf16 bf16x4 __attribute__((ext_vector_type(4)));
typedef __bf16 bf16x2 __attribute__((ext_vector_type(2)));
typedef short  s16x4  __attribute__((ext_vector_type(4)));
typedef float  f32x4  __attribute__((ext_vector_type(4)));
typedef float  f32x16 __attribute__((ext_vector_type(16)));
typedef float  floatx4 __attribute__((ext_vector_type(4)));
typedef unsigned u32x2 __attribute__((ext_vector_type(2)));
typedef unsigned u32x4 __attribute__((ext_vector_type(4)));

#define MFMA16(a, b, c) __builtin_amdgcn_mfma_f32_16x16x32_bf16(a, b, c, 0, 0, 0)
#define MFMA32(a, b, c) __builtin_amdgcn_mfma_f32_32x32x16_bf16(a, b, c, 0, 0, 0)

#define WAITCNT_VM0() __builtin_amdgcn_s_waitcnt(0x0F70)   // vmcnt(0)
#define BARRIER() __builtin_amdgcn_s_barrier()
#define SETPRIO(p) __builtin_amdgcn_s_setprio(p)

__device__ __forceinline__ void glds16(const __bf16* g, __bf16* l) {
    __builtin_amdgcn_global_load_lds(
        (const __attribute__((address_space(1))) void*)g,
        (__attribute__((address_space(3))) void*)l, 16, 0, 0);
}

// ---------------------------------------------------------------------------
// fp32 -> bf16 conversion: X (8M elems) then Wq/Wk/Wv (1M each).
// ---------------------------------------------------------------------------
__global__ __launch_bounds__(256) void convert_kernel(
    const float* __restrict__ X, const float* __restrict__ Wq,
    const float* __restrict__ Wk, const float* __restrict__ Wv,
    __bf16* __restrict__ Xb, __bf16* __restrict__ Wqb,
    __bf16* __restrict__ Wkb, __bf16* __restrict__ Wvb)
{
    int blk = blockIdx.x;
    const float* src; __bf16* dst; size_t base;
    if (blk < 4096)      { src = X;  dst = Xb;  base = (size_t)blk * 2048; }
    else if (blk < 4608) { src = Wq; dst = Wqb; base = (size_t)(blk - 4096) * 2048; }
    else if (blk < 5120) { src = Wk; dst = Wkb; base = (size_t)(blk - 4608) * 2048; }
    else                 { src = Wv; dst = Wvb; base = (size_t)(blk - 5120) * 2048; }
    size_t off = base + (size_t)threadIdx.x * 8;
    floatx4 a = *(const floatx4*)(src + off);
    floatx4 c = *(const floatx4*)(src + off + 4);
    bf16x8 o;
    o[0] = (__bf16)a[0]; o[1] = (__bf16)a[1]; o[2] = (__bf16)a[2]; o[3] = (__bf16)a[3];
    o[4] = (__bf16)c[0]; o[5] = (__bf16)c[1]; o[6] = (__bf16)c[2]; o[7] = (__bf16)c[3];
    *(bf16x8*)(dst + off) = o;
}

// ---------------------------------------------------------------------------
// Fused QKV GEMM: out = Xb @ Wb.T + bias. 128x128 tile, BK=32, double-
// buffered glds staging (32KB LDS -> 4 blocks/CU), ONE s_barrier per step:
//   { stage(s+1 -> nb); frag-read + 16 MFMA on bc; vmcnt(0); barrier }
// blockIdx.x: 0-7 -> Q, 8-15 -> K, 16-23 -> V(transposed).
// ---------------------------------------------------------------------------
__global__ __launch_bounds__(256, 4) void qkv_gemm_kernel(
    const __bf16* __restrict__ Xb,
    const __bf16* __restrict__ Wqb, const __bf16* __restrict__ Wkb,
    const __bf16* __restrict__ Wvb,
    const float* __restrict__ bq, const float* __restrict__ bk,
    const float* __restrict__ bv,
    __bf16* __restrict__ qws, __bf16* __restrict__ kws, __bf16* __restrict__ vws)
{
    __shared__ __bf16 As[2][128 * 32];
    __shared__ __bf16 Bs[2][128 * 32];

    const int tid  = threadIdx.x;
    const int lane = tid & 63;
    const int wave = tid >> 6;
    const int wm   = (wave >> 1) * 64;
    const int wn   = (wave & 1) * 64;
    const int quad = lane >> 4;
    const int l16  = lane & 15;
    const int m0   = blockIdx.y * 128;

    const int sel = blockIdx.x >> 3;
    const bool vmode = (sel == 2);
    const __bf16* Wb = (sel == 0) ? Wqb : (sel == 1) ? Wkb : Wvb;
    const float* bias = (sel == 0) ? bq : (sel == 1) ? bk : bv;
    __bf16* outp = (sel == 0) ? qws : (sel == 1) ? kws : vws;
    const int n0 = (blockIdx.x & 7) * 128;

    const int woffA = vmode ? wm : wn;
    const int woffB = vmode ? wn : wm;

    // staging lane geometry: one glds fills 16 rows x 32 cols (1KB).
    const int srow = lane >> 2;              // row within 16-row block
    const int schk = lane & 3;               // 16B chunk this lane fills
    const int rchk = quad ^ ((l16 >> 1) & 3);   // frag-read chunk

    f32x4 acc[4][4] = {};

    // ---- prologue: stage k-step 0 into buffer 0 (4 glds/wave) ----
    #pragma unroll
    for (int i = 0; i < 2; ++i) {
        int rb = wave * 32 + i * 16;
        int r  = rb + srow;
        int c  = schk ^ ((r >> 1) & 3);
        glds16(Xb + (size_t)(m0 + r) * 1024 + c * 8, &As[0][rb * 32]);
        glds16(Wb + (size_t)(n0 + r) * 1024 + c * 8, &Bs[0][rb * 32]);
    }
    WAITCNT_VM0();
    BARRIER();

    for (int s = 0; s < 32; ++s) {
        const int kn = ((s + 1) & 31) * 32;   // wrap: final restage benign
        const int nb = (s + 1) & 1;
        const int bc = s & 1;
        // ---- stage next k-step (4 glds/wave) ----
        #pragma unroll
        for (int i = 0; i < 2; ++i) {
            int rb = wave * 32 + i * 16;
            int r  = rb + srow;
            int c  = schk ^ ((r >> 1) & 3);
            glds16(Xb + (size_t)(m0 + r) * 1024 + kn + c * 8, &As[nb][rb * 32]);
            glds16(Wb + (size_t)(n0 + r) * 1024 + kn + c * 8, &Bs[nb][rb * 32]);
        }

        const __bf16* Pa_ = vmode ? &As[bc][0] : &Bs[bc][0];
        const __bf16* Pb_ = vmode ? &Bs[bc][0] : &As[bc][0];

        SETPRIO(1);
        bf16x8 af[4], bfr[4];
        #pragma unroll
        for (int a = 0; a < 4; ++a)
            af[a] = *(const bf16x8*)&Pa_[(woffA + a * 16 + l16) * 32 + rchk * 8];
        #pragma unroll
        for (int bb = 0; bb < 4; ++bb)
            bfr[bb] = *(const bf16x8*)&Pb_[(woffB + bb * 16 + l16) * 32 + rchk * 8];
        #pragma unroll
        for (int a = 0; a < 4; ++a)
            #pragma unroll
            for (int bb = 0; bb < 4; ++bb)
                acc[a][bb] = MFMA16(af[a], bfr[bb], acc[a][bb]);
        SETPRIO(0);

        WAITCNT_VM0();          // this iter's stage (issued before compute)
        BARRIER();              // buf nb fully written before anyone reads it
    }

    if (!vmode) {
        #pragma unroll
        for (int a = 0; a < 4; ++a) {
            int n = n0 + woffA + a * 16 + quad * 4;
            floatx4 bv4 = *(const floatx4*)&bias[n];
            int h = n >> 6, d0 = n & 63;
            #pragma unroll
            for (int bb = 0; bb < 4; ++bb) {
                int m = m0 + woffB + bb * 16 + l16;
                int bt = m >> 11, ss = m & 2047;
                bf16x4 o;
                #pragma unroll
                for (int r = 0; r < 4; ++r)
                    o[r] = (__bf16)(acc[a][bb][r] + bv4[r]);
                *(bf16x4*)&outp[((size_t)(bt * 16 + h) * 2048 + ss) * 64 + d0] = o;
            }
        }
    } else {
        #pragma unroll
        for (int a = 0; a < 4; ++a) {
            int m = m0 + woffA + a * 16 + quad * 4;
            int bt = m >> 11, s0 = m & 2047;
            #pragma unroll
            for (int bb = 0; bb < 4; ++bb) {
                int n = n0 + woffB + bb * 16 + l16;
                float bvv = bias[n];
                int h = n >> 6, d = n & 63;
                bf16x4 o;
                #pragma unroll
                for (int r = 0; r < 4; ++r)
                    o[r] = (__bf16)(acc[a][bb][r] + bvv);
                *(bf16x4*)&outp[((size_t)(bt * 16 + h) * 64 + d) * 2048 + s0] = o;
            }
        }
    }
}

// ---------------------------------------------------------------------------
// Attention (R12, 87us measured): grid (64, 8); 8 waves x 32 q-rows.
// KVBLK=128 as two 64-key halves; one barrier per tile. Per half:
//  S^T (2 kg x 4 dk 32x32x16, A=K from LDS, B=Q regs) ->
//  relu^2 pack (f32 vector) -> cvt bf16 -> 4 permlane32_swap per kg ->
//  PV (2 kg x 2 g16 x 2 dt 32x32x16, A=P regs, B=V from LDS).
// ---------------------------------------------------------------------------
__global__ __launch_bounds__(512, 4) void attn_kernel(
    const __bf16* __restrict__ Q, const __bf16* __restrict__ K,
    const __bf16* __restrict__ Vt, const float* __restrict__ mask,
    float* __restrict__ out)
{
    __shared__ __bf16 Ks[2][2][64 * 64];   // [buf][half][key][d], swizzled
    __shared__ __bf16 Vs[2][2][64 * 64];   // [buf][half][d][key], swizzled
    __shared__ float  Ms[2048];            // full mask row for this batch

    const int tid  = threadIdx.x;
    const int lane = tid & 63;
    const int wave = tid >> 6;          // 0..7
    const int l32  = lane & 31;
    const int hi   = lane >> 5;         // 0/1
    const int bh   = blockIdx.x;        // head index -> XCD = bh % 8
    const int b    = bh >> 4;
    const int h    = bh & 15;
    const int q0w  = blockIdx.y * 256 + wave * 32;

    const __bf16* Qb = Q  + (size_t)bh * 2048 * 64;
    const __bf16* Kb = K  + (size_t)bh * 2048 * 64;
    const __bf16* Vb = Vt + (size_t)bh * 64 * 2048;
    const float*  mb = mask + b * 2048;

    // staging lane geometry: per glds a wave fills 8 rows x 64 cols (1KB).
    const int rb = wave * 8;                       // LDS row base this wave
    const int sr = rb + (lane >> 3);               // row this lane reads
    const int sc = ((lane & 7) ^ (sr & 7)) * 8;    // swizzled elem offset

    // Q fragments (B operand of S^T): lane holds Q[q=q0w+l32][d=dk*16+hi*8+j]
    bf16x8 aq[4];
    #pragma unroll
    for (int dk = 0; dk < 4; ++dk)
        aq[dk] = *(const bf16x8*)(Qb +
            (size_t)(q0w + l32) * 64 + dk * 16 + hi * 8);

    f32x16 co0 = {}, co1 = {};   // ctx: rows=q (C layout), cols=d (dt*32+l32)

    // ---- prologue: stage tile 0 (4 glds/wave) + mask row (1 glds/wave) ----
    glds16(Kb + (size_t)sr * 64 + sc,        &Ks[0][0][rb * 64]);
    glds16(Kb + (size_t)(64 + sr) * 64 + sc, &Ks[0][1][rb * 64]);
    glds16(Vb + (size_t)sr * 2048 + sc,      &Vs[0][0][rb * 64]);
    glds16(Vb + (size_t)sr * 2048 + 64 + sc, &Vs[0][1][rb * 64]);
    glds16((const __bf16*)mb + (size_t)wave * 512 + lane * 8,
           (__bf16*)Ms + wave * 512);
    WAITCNT_VM0();
    BARRIER();

    for (int t = 0; t < 16; ++t) {
        const int kn = ((t + 1) & 15) * 128;  // wrap: final restage benign
        const int nb = (t + 1) & 1;
        const int cb = t & 1;
        // ---- stage next 128-key tile (4 glds/wave) ----
        glds16(Kb + (size_t)(kn + sr) * 64 + sc,       &Ks[nb][0][rb * 64]);
        glds16(Kb + (size_t)(kn + 64 + sr) * 64 + sc,  &Ks[nb][1][rb * 64]);
        glds16(Vb + (size_t)sr * 2048 + kn + sc,       &Vs[nb][0][rb * 64]);
        glds16(Vb + (size_t)sr * 2048 + kn + 64 + sc,  &Vs[nb][1][rb * 64]);

        #pragma unroll
        for (int hf = 0; hf < 2; ++hf) {
            const __bf16* Kt = &Ks[cb][hf][0];
            const __bf16* Vtl = &Vs[cb][hf][0];
            const int k0 = t * 128 + hf * 64;

            // ---- phase 1: S^T = K Q^T, two 32-key groups, K=16 chain ----
            f32x16 st0 = {}, st1 = {};
            SETPRIO(1);
            #pragma unroll
            for (int dk = 0; dk < 4; ++dk) {
                const int g = dk * 2 + hi;             // global d-chunk
                const int c0 = (g ^ (l32 & 7)) * 8;    // swizzled (row&7 dep)
                bf16x8 ak0 = *(const bf16x8*)&Kt[l32 * 64 + c0];
                bf16x8 ak1 = *(const bf16x8*)&Kt[(32 + l32) * 64 + c0];
                st0 = MFMA32(ak0, aq[dk], st0);
                st1 = MFMA32(ak1, aq[dk], st1);
            }
            SETPRIO(0);

            // ---- phase 2+3 per 32-key group ----
            #pragma unroll
            for (int kg = 0; kg < 2; ++kg) {
                const f32x16 s = kg ? st1 : st0;
                const f32x4 zero4 = {};
                unsigned W[4][2];
                #pragma unroll
                for (int G = 0; G < 4; ++G) {
                    f32x4 v;
                    v[0] = s[G * 4 + 0]; v[1] = s[G * 4 + 1];
                    v[2] = s[G * 4 + 2]; v[3] = s[G * 4 + 3];
                    f32x4 mk = *(const f32x4*)&Ms[k0 + kg * 32 + G * 8 + hi * 4];
                    v = v * 0.125f + mk;                      // v_pk_fma_f32
                    v = __builtin_elementwise_max(v, zero4);  // v_pk_max_f32
                    v = v * v;                                // v_pk_mul_f32
                    bf16x2 w0, w1;
                    w0[0] = (__bf16)v[0]; w0[1] = (__bf16)v[1];
                    w1[0] = (__bf16)v[2]; w1[1] = (__bf16)v[3];
                    W[G][0] = __builtin_bit_cast(unsigned, w0);
                    W[G][1] = __builtin_bit_cast(unsigned, w1);
                }
                // repack to K=16 A-frags: lane l<->l+32 word exchange.
                u32x2 s00 = __builtin_amdgcn_permlane32_swap(W[0][0], W[1][0], false, false);
                u32x2 s01 = __builtin_amdgcn_permlane32_swap(W[0][1], W[1][1], false, false);
                u32x2 s10 = __builtin_amdgcn_permlane32_swap(W[2][0], W[3][0], false, false);
                u32x2 s11 = __builtin_amdgcn_permlane32_swap(W[2][1], W[3][1], false, false);
                u32x4 f0, f1;
                f0[0] = s00[0]; f0[1] = s01[0]; f0[2] = s00[1]; f0[3] = s01[1];
                f1[0] = s10[0]; f1[1] = s11[0]; f1[2] = s10[1]; f1[3] = s11[1];
                bf16x8 pa0 = __builtin_bit_cast(bf16x8, f0);   // keys kg*32+ 0..15
                bf16x8 pa1 = __builtin_bit_cast(bf16x8, f1);   // keys kg*32+16..31

                // ---- PV: co[dt] += P V, B = V^T slice from LDS ----
                SETPRIO(1);
                #pragma unroll
                for (int dt = 0; dt < 2; ++dt) {
                    const int d = dt * 32 + l32;
                    const int ch0 = (kg * 4 + hi) ^ (d & 7);
                    const int ch1 = (kg * 4 + 2 + hi) ^ (d & 7);
                    bf16x8 vb0 = *(const bf16x8*)&Vtl[d * 64 + ch0 * 8];
                    bf16x8 vb1 = *(const bf16x8*)&Vtl[d * 64 + ch1 * 8];
                    if (dt == 0) {
                        co0 = MFMA32(pa0, vb0, co0);
                        co0 = MFMA32(pa1, vb1, co0);
                    } else {
                        co1 = MFMA32(pa0, vb0, co1);
                        co1 = MFMA32(pa1, vb1, co1);
                    }
                }
                SETPRIO(0);
            }
        }

        WAITCNT_VM0();          // this iter's stage (issued ~3000 cyc ago)
        BARRIER();              // buf nb fully written before anyone reads it
    }

    // Epilogue: q = q0w + (r&3)+8*(r>>2)+4*hi, d = dt*32 + l32.
    #pragma unroll
    for (int r = 0; r < 16; ++r) {
        int q = q0w + (r & 3) + 8 * (r >> 2) + 4 * hi;
        float* orow = &out[(((size_t)b * 2048 + q) * 16 + h) * 64];
        orow[l32]      = co0[r];
        orow[32 + l32] = co1[r];
    }
}

// ---------------------------------------------------------------------------
extern "C" void kernel_launch(void* const* d_in, const int* in_sizes, int n_in,
                              void* d_out, int out_size, void* d_ws, size_t ws_size,
                              hipStream_t stream) {
    const float* hidden = (const float*)d_in[0];   // [4,2048,1024]
    const float* mask   = (const float*)d_in[1];   // [4,1,1,2048]
    const float* Wq     = (const float*)d_in[2];
    const float* bq     = (const float*)d_in[3];
    const float* Wk     = (const float*)d_in[4];
    const float* bk     = (const float*)d_in[5];
    const float* Wv     = (const float*)d_in[6];
    const float* bv     = (const float*)d_in[7];
    float* out = (float*)d_out;

    __bf16* qws = (__bf16*)d_ws;                       // [64][2048][64]
    __bf16* kws = qws + (size_t)64 * 2048 * 64;        // [64][2048][64]
    __bf16* vws = kws + (size_t)64 * 2048 * 64;        // [64][64][2048]
    __bf16* Xb  = vws + (size_t)64 * 2048 * 64;        // [8192][1024]
    __bf16* Wqb = Xb  + (size_t)8192 * 1024;
    __bf16* Wkb = Wqb + (size_t)1024 * 1024;
    __bf16* Wvb = Wkb + (size_t)1024 * 1024;

    convert_kernel<<<dim3(5632), dim3(256), 0, stream>>>(hidden, Wq, Wk, Wv,
                                                         Xb, Wqb, Wkb, Wvb);
    qkv_gemm_kernel<<<dim3(24, 64), dim3(256), 0, stream>>>(Xb, Wqb, Wkb, Wvb,
                                                            bq, bk, bv,
                                                            qws, kws, vws);
    attn_kernel<<<dim3(64, 8), dim3(512), 0, stream>>>(qws, kws, vws, mask, out);
}

// Round 9
// 240.917 us; speedup vs baseline: 1.0010x; 1.0010x over previous
//
#include <hip/hip_runtime.h>

// MI355X / gfx950. bf16 MFMA BERT attention with relu^2 "softmax".
// R15: qkv ported to the 8-phase counted-vmcnt schedule (T3+T4, m201-style).
// R10/R14 both sat at ~542 TF = the 2-phase ceiling (m233); occupancy moves
// (2 vs 4 blocks/CU) were null, matching the regime-gate: only the phase-
// interleaved counted-vmcnt pipeline breaks the ceiling.
// qkv geometry: BM=256 x BN=128, BK=64, 8 waves (512 thr), TRIPLE-buffered
// LDS (3x48KB=144KB, 1 block/CU), grid (24,32)=768 blocks = 3 perfect
// rounds. Per K-tile: 2 phases of {8 ds_read ; issue 3 glds(tile s+2) ;
// [p1: vmcnt(6)] ; barrier ; setprio; 16 MFMA ; setprio; barrier}.
// vmcnt(6) = wait tile s+1 landed while s+2's 6 glds stay in flight --
// never vmcnt(0) in the main loop.
// attn: R12 structure unchanged (87us measured best).
// 16x16x32 layouts: A: lane l holds A[m=l&15][k=(l>>4)*8+j]; B sym.;
// C/D: lane l reg r holds D[row=(l>>4)*4+r][col=l&15].
// 32x32x16: C/D row=(r&3)+8*(r>>2)+4*(l>>5), col=l&31.

typedef __bf16 bf16x8 __attribute__((ext_vector_type(8)));
typedef __bf16 bf16x4 __attribute__((ext_vector_type(4)));
typedef __bf16 bf16x2 __attribute__((ext_vector_type(2)));
typedef short  s16x4  __attribute__((ext_vector_type(4)));
typedef float  f32x4  __attribute__((ext_vector_type(4)));
typedef float  f32x16 __attribute__((ext_vector_type(16)));
typedef float  floatx4 __attribute__((ext_vector_type(4)));
typedef unsigned u32x2 __attribute__((ext_vector_type(2)));
typedef unsigned u32x4 __attribute__((ext_vector_type(4)));

#define MFMA16(a, b, c) __builtin_amdgcn_mfma_f32_16x16x32_bf16(a, b, c, 0, 0, 0)
#define MFMA32(a, b, c) __builtin_amdgcn_mfma_f32_32x32x16_bf16(a, b, c, 0, 0, 0)

#define WAITCNT_VM0() __builtin_amdgcn_s_waitcnt(0x0F70)   // vmcnt(0)
#define WAITCNT_VM6() __builtin_amdgcn_s_waitcnt(0x0F76)   // vmcnt(6)
#define BARRIER() __builtin_amdgcn_s_barrier()
#define SETPRIO(p) __builtin_amdgcn_s_setprio(p)

__device__ __forceinline__ void glds16(const __bf16* g, __bf16* l) {
    __builtin_amdgcn_global_load_lds(
        (const __attribute__((address_space(1))) void*)g,
        (__attribute__((address_space(3))) void*)l, 16, 0, 0);
}

// ---------------------------------------------------------------------------
// fp32 -> bf16 conversion: X (8M elems) then Wq/Wk/Wv (1M each).
// ---------------------------------------------------------------------------
__global__ __launch_bounds__(256) void convert_kernel(
    const float* __restrict__ X, const float* __restrict__ Wq,
    const float* __restrict__ Wk, const float* __restrict__ Wv,
    __bf16* __restrict__ Xb, __bf16* __restrict__ Wqb,
    __bf16* __restrict__ Wkb, __bf16* __restrict__ Wvb)
{
    int blk = blockIdx.x;
    const float* src; __bf16* dst; size_t base;
    if (blk < 4096)      { src = X;  dst = Xb;  base = (size_t)blk * 2048; }
    else if (blk < 4608) { src = Wq; dst = Wqb; base = (size_t)(blk - 4096) * 2048; }
    else if (blk < 5120) { src = Wk; dst = Wkb; base = (size_t)(blk - 4608) * 2048; }
    else                 { src = Wv; dst = Wvb; base = (size_t)(blk - 5120) * 2048; }
    size_t off = base + (size_t)threadIdx.x * 8;
    floatx4 a = *(const floatx4*)(src + off);
    floatx4 c = *(const floatx4*)(src + off + 4);
    bf16x8 o;
    o[0] = (__bf16)a[0]; o[1] = (__bf16)a[1]; o[2] = (__bf16)a[2]; o[3] = (__bf16)a[3];
    o[4] = (__bf16)c[0]; o[5] = (__bf16)c[1]; o[6] = (__bf16)c[2]; o[7] = (__bf16)c[3];
    *(bf16x8*)(dst + off) = o;
}

// ---------------------------------------------------------------------------
// Fused QKV GEMM, 8-phase counted-vmcnt schedule.
// out = Xb @ Wb.T + bias. BM=256, BN=128, BK=64; 8 waves; triple-buffered.
// blockIdx.x: 0-7 -> Q, 8-15 -> K, 16-23 -> V(transposed); y: m-tile (32).
// Per wave per K-tile: 6 glds staged for tile s+2 (A:4, B:2); 2 phases of
// 16 MFMA each; vmcnt(6) once per tile (in phase 1, before its barrier).
// ---------------------------------------------------------------------------
__global__ __launch_bounds__(512, 2) void qkv_gemm_kernel(
    const __bf16* __restrict__ Xb,
    const __bf16* __restrict__ Wqb, const __bf16* __restrict__ Wkb,
    const __bf16* __restrict__ Wvb,
    const float* __restrict__ bq, const float* __restrict__ bk,
    const float* __restrict__ bv,
    __bf16* __restrict__ qws, __bf16* __restrict__ kws, __bf16* __restrict__ vws)
{
    __shared__ __bf16 As[3][256 * 64];   // 96KB: X-tile rows [m0,m0+256)
    __shared__ __bf16 Bs[3][128 * 64];   // 48KB: W-tile rows [n0,n0+128)

    const int tid  = threadIdx.x;
    const int lane = tid & 63;
    const int wave = tid >> 6;           // 0..7
    const int quad = lane >> 4;
    const int l16  = lane & 15;
    const int m0   = blockIdx.y * 256;

    const int sel = blockIdx.x >> 3;
    const bool vmode = (sel == 2);
    const __bf16* Wb = (sel == 0) ? Wqb : (sel == 1) ? Wkb : Wvb;
    const float* bias = (sel == 0) ? bq : (sel == 1) ? bk : bv;
    __bf16* outp = (sel == 0) ? qws : (sel == 1) ? kws : vws;
    const int n0 = (blockIdx.x & 7) * 128;

    // Per-wave quadrant: A-operand rows (Pa_) x B-operand rows (Pb_).
    // vmode=0: Pa_=Bs(128 rows, N side), Pb_=As(256 rows, M side).
    // vmode=1: swapped (transposed V output).
    const int wA = vmode ? (wave & 3) * 64 : (wave >> 2) * 64;
    const int wB = vmode ? (wave >> 2) * 64 : (wave & 3) * 64;

    // staging lane geometry: one glds fills 8 rows x 64 cols (1KB).
    const int srow = lane >> 3;              // row within 8-row block
    const int schk = lane & 7;               // 16B chunk this lane fills

    f32x4 acc[4][4] = {};

    // stage helpers: tile kt (K-tile index) into buffer bb.
    // A: i=0..3 covers rows wave*32..+32; B: i=0..1 covers rows wave*16..+16.
#define QKV_STAGE_A(bb, kt, i) { \
        int rb_ = wave * 32 + (i) * 8; int r_ = rb_ + srow; \
        int c_ = schk ^ (r_ & 7); \
        glds16(Xb + (size_t)(m0 + r_) * 1024 + (kt) * 64 + c_ * 8, \
               &As[bb][rb_ * 64]); }
#define QKV_STAGE_B(bb, kt, i) { \
        int rb_ = wave * 16 + (i) * 8; int r_ = rb_ + srow; \
        int c_ = schk ^ (r_ & 7); \
        glds16(Wb + (size_t)(n0 + r_) * 1024 + (kt) * 64 + c_ * 8, \
               &Bs[bb][rb_ * 64]); }

    // ---- prologue: stage tiles 0 and 1 (12 glds/wave) ----
    #pragma unroll
    for (int i = 0; i < 4; ++i) QKV_STAGE_A(0, 0, i);
    #pragma unroll
    for (int i = 0; i < 2; ++i) QKV_STAGE_B(0, 0, i);
    #pragma unroll
    for (int i = 0; i < 4; ++i) QKV_STAGE_A(1, 1, i);
    #pragma unroll
    for (int i = 0; i < 2; ++i) QKV_STAGE_B(1, 1, i);
    WAITCNT_VM6();               // tile 0 landed; tile 1's 6 in flight
    BARRIER();

    for (int s = 0; s < 16; ++s) {
        const int cb  = s % 3;
        const int pb  = (s + 2) % 3;
        const int kt2 = (s + 2) & 15;        // wrap: benign restage
        const __bf16* Pa_ = vmode ? &As[cb][0] : &Bs[cb][0];
        const __bf16* Pb_ = vmode ? &Bs[cb][0] : &As[cb][0];

        #pragma unroll
        for (int p = 0; p < 2; ++p) {
            // ---- ds-load this phase's fragments (K-half p) ----
            bf16x8 af[4], bfr[4];
            #pragma unroll
            for (int a = 0; a < 4; ++a)
                af[a] = *(const bf16x8*)&Pa_[(wA + a * 16 + l16) * 64 +
                                             (((p * 4 + quad) ^ (l16 & 7)) * 8)];
            #pragma unroll
            for (int bb = 0; bb < 4; ++bb)
                bfr[bb] = *(const bf16x8*)&Pb_[(wB + bb * 16 + l16) * 64 +
                                               (((p * 4 + quad) ^ (l16 & 7)) * 8)];
            // ---- issue half of tile s+2's staging (3 glds) ----
            QKV_STAGE_A(pb, kt2, 2 * p);
            QKV_STAGE_A(pb, kt2, 2 * p + 1);
            QKV_STAGE_B(pb, kt2, p);

            if (p == 1) WAITCNT_VM6();  // tile s+1 landed; s+2's 6 in flight
            BARRIER();

            SETPRIO(1);
            #pragma unroll
            for (int a = 0; a < 4; ++a)
                #pragma unroll
                for (int bb = 0; bb < 4; ++bb)
                    acc[a][bb] = MFMA16(af[a], bfr[bb], acc[a][bb]);
            SETPRIO(0);
            BARRIER();
        }
    }

#undef QKV_STAGE_A
#undef QKV_STAGE_B

    if (!vmode) {
        #pragma unroll
        for (int a = 0; a < 4; ++a) {
            int n = n0 + wA + a * 16 + quad * 4;
            floatx4 bv4 = *(const floatx4*)&bias[n];
            int h = n >> 6, d0 = n & 63;
            #pragma unroll
            for (int bb = 0; bb < 4; ++bb) {
                int m = m0 + wB + bb * 16 + l16;
                int bt = m >> 11, ss = m & 2047;
                bf16x4 o;
                #pragma unroll
                for (int r = 0; r < 4; ++r)
                    o[r] = (__bf16)(acc[a][bb][r] + bv4[r]);
                *(bf16x4*)&outp[((size_t)(bt * 16 + h) * 2048 + ss) * 64 + d0] = o;
            }
        }
    } else {
        #pragma unroll
        for (int a = 0; a < 4; ++a) {
            int m = m0 + wA + a * 16 + quad * 4;
            int bt = m >> 11, s0 = m & 2047;
            #pragma unroll
            for (int bb = 0; bb < 4; ++bb) {
                int n = n0 + wB + bb * 16 + l16;
                float bvv = bias[n];
                int h = n >> 6, d = n & 63;
                bf16x4 o;
                #pragma unroll
                for (int r = 0; r < 4; ++r)
                    o[r] = (__bf16)(acc[a][bb][r] + bvv);
                *(bf16x4*)&outp[((size_t)(bt * 16 + h) * 64 + d) * 2048 + s0] = o;
            }
        }
    }
}

// ---------------------------------------------------------------------------
// Attention (R12, 87us measured): grid (64, 8); 8 waves x 32 q-rows.
// KVBLK=128 as two 64-key halves; one barrier per tile. Per half:
//  S^T (2 kg x 4 dk 32x32x16, A=K from LDS, B=Q regs) ->
//  relu^2 pack (f32 vector) -> cvt bf16 -> 4 permlane32_swap per kg ->
//  PV (2 kg x 2 g16 x 2 dt 32x32x16, A=P regs, B=V from LDS).
// ---------------------------------------------------------------------------
__global__ __launch_bounds__(512, 4) void attn_kernel(
    const __bf16* __restrict__ Q, const __bf16* __restrict__ K,
    const __bf16* __restrict__ Vt, const float* __restrict__ mask,
    float* __restrict__ out)
{
    __shared__ __bf16 Ks[2][2][64 * 64];   // [buf][half][key][d], swizzled
    __shared__ __bf16 Vs[2][2][64 * 64];   // [buf][half][d][key], swizzled
    __shared__ float  Ms[2048];            // full mask row for this batch

    const int tid  = threadIdx.x;
    const int lane = tid & 63;
    const int wave = tid >> 6;          // 0..7
    const int l32  = lane & 31;
    const int hi   = lane >> 5;         // 0/1
    const int bh   = blockIdx.x;        // head index -> XCD = bh % 8
    const int b    = bh >> 4;
    const int h    = bh & 15;
    const int q0w  = blockIdx.y * 256 + wave * 32;

    const __bf16* Qb = Q  + (size_t)bh * 2048 * 64;
    const __bf16* Kb = K  + (size_t)bh * 2048 * 64;
    const __bf16* Vb = Vt + (size_t)bh * 64 * 2048;
    const float*  mb = mask + b * 2048;

    // staging lane geometry: per glds a wave fills 8 rows x 64 cols (1KB).
    const int rb = wave * 8;                       // LDS row base this wave
    const int sr = rb + (lane >> 3);               // row this lane reads
    const int sc = ((lane & 7) ^ (sr & 7)) * 8;    // swizzled elem offset

    // Q fragments (B operand of S^T): lane holds Q[q=q0w+l32][d=dk*16+hi*8+j]
    bf16x8 aq[4];
    #pragma unroll
    for (int dk = 0; dk < 4; ++dk)
        aq[dk] = *(const bf16x8*)(Qb +
            (size_t)(q0w + l32) * 64 + dk * 16 + hi * 8);

    f32x16 co0 = {}, co1 = {};   // ctx: rows=q (C layout), cols=d (dt*32+l32)

    // ---- prologue: stage tile 0 (4 glds/wave) + mask row (1 glds/wave) ----
    glds16(Kb + (size_t)sr * 64 + sc,        &Ks[0][0][rb * 64]);
    glds16(Kb + (size_t)(64 + sr) * 64 + sc, &Ks[0][1][rb * 64]);
    glds16(Vb + (size_t)sr * 2048 + sc,      &Vs[0][0][rb * 64]);
    glds16(Vb + (size_t)sr * 2048 + 64 + sc, &Vs[0][1][rb * 64]);
    glds16((const __bf16*)mb + (size_t)wave * 512 + lane * 8,
           (__bf16*)Ms + wave * 512);
    WAITCNT_VM0();
    BARRIER();

    for (int t = 0; t < 16; ++t) {
        const int kn = ((t + 1) & 15) * 128;  // wrap: final restage benign
        const int nb = (t + 1) & 1;
        const int cb = t & 1;
        // ---- stage next 128-key tile (4 glds/wave) ----
        glds16(Kb + (size_t)(kn + sr) * 64 + sc,       &Ks[nb][0][rb * 64]);
        glds16(Kb + (size_t)(kn + 64 + sr) * 64 + sc,  &Ks[nb][1][rb * 64]);
        glds16(Vb + (size_t)sr * 2048 + kn + sc,       &Vs[nb][0][rb * 64]);
        glds16(Vb + (size_t)sr * 2048 + kn + 64 + sc,  &Vs[nb][1][rb * 64]);

        #pragma unroll
        for (int hf = 0; hf < 2; ++hf) {
            const __bf16* Kt = &Ks[cb][hf][0];
            const __bf16* Vtl = &Vs[cb][hf][0];
            const int k0 = t * 128 + hf * 64;

            // ---- phase 1: S^T = K Q^T, two 32-key groups, K=16 chain ----
            f32x16 st0 = {}, st1 = {};
            SETPRIO(1);
            #pragma unroll
            for (int dk = 0; dk < 4; ++dk) {
                const int g = dk * 2 + hi;             // global d-chunk
                const int c0 = (g ^ (l32 & 7)) * 8;    // swizzled (row&7 dep)
                bf16x8 ak0 = *(const bf16x8*)&Kt[l32 * 64 + c0];
                bf16x8 ak1 = *(const bf16x8*)&Kt[(32 + l32) * 64 + c0];
                st0 = MFMA32(ak0, aq[dk], st0);
                st1 = MFMA32(ak1, aq[dk], st1);
            }
            SETPRIO(0);

            // ---- phase 2+3 per 32-key group ----
            #pragma unroll
            for (int kg = 0; kg < 2; ++kg) {
                const f32x16 s = kg ? st1 : st0;
                const f32x4 zero4 = {};
                unsigned W[4][2];
                #pragma unroll
                for (int G = 0; G < 4; ++G) {
                    f32x4 v;
                    v[0] = s[G * 4 + 0]; v[1] = s[G * 4 + 1];
                    v[2] = s[G * 4 + 2]; v[3] = s[G * 4 + 3];
                    f32x4 mk = *(const f32x4*)&Ms[k0 + kg * 32 + G * 8 + hi * 4];
                    v = v * 0.125f + mk;                      // v_pk_fma_f32
                    v = __builtin_elementwise_max(v, zero4);  // v_pk_max_f32
                    v = v * v;                                // v_pk_mul_f32
                    bf16x2 w0, w1;
                    w0[0] = (__bf16)v[0]; w0[1] = (__bf16)v[1];
                    w1[0] = (__bf16)v[2]; w1[1] = (__bf16)v[3];
                    W[G][0] = __builtin_bit_cast(unsigned, w0);
                    W[G][1] = __builtin_bit_cast(unsigned, w1);
                }
                // repack to K=16 A-frags: lane l<->l+32 word exchange.
                u32x2 s00 = __builtin_amdgcn_permlane32_swap(W[0][0], W[1][0], false, false);
                u32x2 s01 = __builtin_amdgcn_permlane32_swap(W[0][1], W[1][1], false, false);
                u32x2 s10 = __builtin_amdgcn_permlane32_swap(W[2][0], W[3][0], false, false);
                u32x2 s11 = __builtin_amdgcn_permlane32_swap(W[2][1], W[3][1], false, false);
                u32x4 f0, f1;
                f0[0] = s00[0]; f0[1] = s01[0]; f0[2] = s00[1]; f0[3] = s01[1];
                f1[0] = s10[0]; f1[1] = s11[0]; f1[2] = s10[1]; f1[3] = s11[1];
                bf16x8 pa0 = __builtin_bit_cast(bf16x8, f0);   // keys kg*32+ 0..15
                bf16x8 pa1 = __builtin_bit_cast(bf16x8, f1);   // keys kg*32+16..31

                // ---- PV: co[dt] += P V, B = V^T slice from LDS ----
                SETPRIO(1);
                #pragma unroll
                for (int dt = 0; dt < 2; ++dt) {
                    const int d = dt * 32 + l32;
                    const int ch0 = (kg * 4 + hi) ^ (d & 7);
                    const int ch1 = (kg * 4 + 2 + hi) ^ (d & 7);
                    bf16x8 vb0 = *(const bf16x8*)&Vtl[d * 64 + ch0 * 8];
                    bf16x8 vb1 = *(const bf16x8*)&Vtl[d * 64 + ch1 * 8];
                    if (dt == 0) {
                        co0 = MFMA32(pa0, vb0, co0);
                        co0 = MFMA32(pa1, vb1, co0);
                    } else {
                        co1 = MFMA32(pa0, vb0, co1);
                        co1 = MFMA32(pa1, vb1, co1);
                    }
                }
                SETPRIO(0);
            }
        }

        WAITCNT_VM0();          // this iter's stage (issued ~3000 cyc ago)
        BARRIER();              // buf nb fully written before anyone reads it
    }

    // Epilogue: q = q0w + (r&3)+8*(r>>2)+4*hi, d = dt*32 + l32.
    #pragma unroll
    for (int r = 0; r < 16; ++r) {
        int q = q0w + (r & 3) + 8 * (r >> 2) + 4 * hi;
        float* orow = &out[(((size_t)b * 2048 + q) * 16 + h) * 64];
        orow[l32]      = co0[r];
        orow[32 + l32] = co1[r];
    }
}

// ---------------------------------------------------------------------------
extern "C" void kernel_launch(void* const* d_in, const int* in_sizes, int n_in,
                              void* d_out, int out_size, void* d_ws, size_t ws_size,
                              hipStream_t stream) {
    const float* hidden = (const float*)d_in[0];   // [4,2048,1024]
    const float* mask   = (const float*)d_in[1];   // [4,1,1,2048]
    const float* Wq     = (const float*)d_in[2];
    const float* bq     = (const float*)d_in[3];
    const float* Wk     = (const float*)d_in[4];
    const float* bk     = (const float*)d_in[5];
    const float* Wv     = (const float*)d_in[6];
    const float* bv     = (const float*)d_in[7];
    float* out = (float*)d_out;

    __bf16* qws = (__bf16*)d_ws;                       // [64][2048][64]
    __bf16* kws = qws + (size_t)64 * 2048 * 64;        // [64][2048][64]
    __bf16* vws = kws + (size_t)64 * 2048 * 64;        // [64][64][2048]
    __bf16* Xb  = vws + (size_t)64 * 2048 * 64;        // [8192][1024]
    __bf16* Wqb = Xb  + (size_t)8192 * 1024;
    __bf16* Wkb = Wqb + (size_t)1024 * 1024;
    __bf16* Wvb = Wkb + (size_t)1024 * 1024;

    convert_kernel<<<dim3(5632), dim3(256), 0, stream>>>(hidden, Wq, Wk, Wv,
                                                         Xb, Wqb, Wkb, Wvb);
    qkv_gemm_kernel<<<dim3(24, 32), dim3(512), 0, stream>>>(Xb, Wqb, Wkb, Wvb,
                                                            bq, bk, bv,
                                                            qws, kws, vws);
    attn_kernel<<<dim3(64, 8), dim3(512), 0, stream>>>(qws, kws, vws, mask, out);
}

// Round 10
// 234.300 us; speedup vs baseline: 1.0293x; 1.0282x over previous
//
#include <hip/hip_runtime.h>

// MI355X / gfx950. bf16 MFMA BERT attention with relu^2 "softmax".
// R16: attn re-derived as LDS-THROUGHPUT-bound (per CU: 8192 b128 reads
// ~98k cyc + 33k conflict > MFMA floor 66k; kernel 211k). Fix: 2x MFMA per
// LDS read. Each wave now owns 64 q-rows (two B-operand sets aq[2]):
//  - S^T: 8 K A-frags held in regs, reused for both q-groups -> 8 reads /
//    16 MFMA (was 8/8).
//  - PV: per kg, 4 V B-frags read once, reused for both q-groups -> 8
//    reads / 16 MFMA (was 8/8).
// Per-CU LDS reads halve (98k -> 49k cyc) -> below the 66k MFMA floor.
// Block = 4 waves x 64q = 256 thr; grid (64,8); LDS 72KB -> 2 blocks/CU.
// VGPR ~200-230 (st 64 + co 64 + akf 32 + aq 32) -- launch_bounds(256,2).
// qkv (R15 8-phase) and convert unchanged.
// 32x32x16 layouts (HW-verified C/D):
//   A: lane l holds A[m=l&31][k=(l>>5)*8+j]
//   B: lane l holds B[k=(l>>5)*8+j][n=l&31]
//   C/D: lane l reg r holds D[row=(r&3)+8*(r>>2)+4*(l>>5)][col=l&31]

typedef __bf16 bf16x8 __attribute__((ext_vector_type(8)));
typedef __bf16 bf16x4 __attribute__((ext_vector_type(4)));
typedef __bf16 bf16x2 __attribute__((ext_vector_type(2)));
typedef short  s16x4  __attribute__((ext_vector_type(4)));
typedef float  f32x4  __attribute__((ext_vector_type(4)));
typedef float  f32x16 __attribute__((ext_vector_type(16)));
typedef float  floatx4 __attribute__((ext_vector_type(4)));
typedef unsigned u32x2 __attribute__((ext_vector_type(2)));
typedef unsigned u32x4 __attribute__((ext_vector_type(4)));

#define MFMA16(a, b, c) __builtin_amdgcn_mfma_f32_16x16x32_bf16(a, b, c, 0, 0, 0)
#define MFMA32(a, b, c) __builtin_amdgcn_mfma_f32_32x32x16_bf16(a, b, c, 0, 0, 0)

#define WAITCNT_VM0() __builtin_amdgcn_s_waitcnt(0x0F70)   // vmcnt(0)
#define WAITCNT_VM6() __builtin_amdgcn_s_waitcnt(0x0F76)   // vmcnt(6)
#define BARRIER() __builtin_amdgcn_s_barrier()
#define SETPRIO(p) __builtin_amdgcn_s_setprio(p)

__device__ __forceinline__ void glds16(const __bf16* g, __bf16* l) {
    __builtin_amdgcn_global_load_lds(
        (const __attribute__((address_space(1))) void*)g,
        (__attribute__((address_space(3))) void*)l, 16, 0, 0);
}

// ---------------------------------------------------------------------------
// fp32 -> bf16 conversion: X (8M elems) then Wq/Wk/Wv (1M each).
// ---------------------------------------------------------------------------
__global__ __launch_bounds__(256) void convert_kernel(
    const float* __restrict__ X, const float* __restrict__ Wq,
    const float* __restrict__ Wk, const float* __restrict__ Wv,
    __bf16* __restrict__ Xb, __bf16* __restrict__ Wqb,
    __bf16* __restrict__ Wkb, __bf16* __restrict__ Wvb)
{
    int blk = blockIdx.x;
    const float* src; __bf16* dst; size_t base;
    if (blk < 4096)      { src = X;  dst = Xb;  base = (size_t)blk * 2048; }
    else if (blk < 4608) { src = Wq; dst = Wqb; base = (size_t)(blk - 4096) * 2048; }
    else if (blk < 5120) { src = Wk; dst = Wkb; base = (size_t)(blk - 4608) * 2048; }
    else                 { src = Wv; dst = Wvb; base = (size_t)(blk - 5120) * 2048; }
    size_t off = base + (size_t)threadIdx.x * 8;
    floatx4 a = *(const floatx4*)(src + off);
    floatx4 c = *(const floatx4*)(src + off + 4);
    bf16x8 o;
    o[0] = (__bf16)a[0]; o[1] = (__bf16)a[1]; o[2] = (__bf16)a[2]; o[3] = (__bf16)a[3];
    o[4] = (__bf16)c[0]; o[5] = (__bf16)c[1]; o[6] = (__bf16)c[2]; o[7] = (__bf16)c[3];
    *(bf16x8*)(dst + off) = o;
}

// ---------------------------------------------------------------------------
// Fused QKV GEMM, 8-phase counted-vmcnt schedule (R15, unchanged).
// out = Xb @ Wb.T + bias. BM=256, BN=128, BK=64; 8 waves; triple-buffered.
// blockIdx.x: 0-7 -> Q, 8-15 -> K, 16-23 -> V(transposed); y: m-tile (32).
// ---------------------------------------------------------------------------
__global__ __launch_bounds__(512, 2) void qkv_gemm_kernel(
    const __bf16* __restrict__ Xb,
    const __bf16* __restrict__ Wqb, const __bf16* __restrict__ Wkb,
    const __bf16* __restrict__ Wvb,
    const float* __restrict__ bq, const float* __restrict__ bk,
    const float* __restrict__ bv,
    __bf16* __restrict__ qws, __bf16* __restrict__ kws, __bf16* __restrict__ vws)
{
    __shared__ __bf16 As[3][256 * 64];   // 96KB: X-tile rows [m0,m0+256)
    __shared__ __bf16 Bs[3][128 * 64];   // 48KB: W-tile rows [n0,n0+128)

    const int tid  = threadIdx.x;
    const int lane = tid & 63;
    const int wave = tid >> 6;           // 0..7
    const int quad = lane >> 4;
    const int l16  = lane & 15;
    const int m0   = blockIdx.y * 256;

    const int sel = blockIdx.x >> 3;
    const bool vmode = (sel == 2);
    const __bf16* Wb = (sel == 0) ? Wqb : (sel == 1) ? Wkb : Wvb;
    const float* bias = (sel == 0) ? bq : (sel == 1) ? bk : bv;
    __bf16* outp = (sel == 0) ? qws : (sel == 1) ? kws : vws;
    const int n0 = (blockIdx.x & 7) * 128;

    const int wA = vmode ? (wave & 3) * 64 : (wave >> 2) * 64;
    const int wB = vmode ? (wave >> 2) * 64 : (wave & 3) * 64;

    const int srow = lane >> 3;              // row within 8-row block
    const int schk = lane & 7;               // 16B chunk this lane fills

    f32x4 acc[4][4] = {};

#define QKV_STAGE_A(bb, kt, i) { \
        int rb_ = wave * 32 + (i) * 8; int r_ = rb_ + srow; \
        int c_ = schk ^ (r_ & 7); \
        glds16(Xb + (size_t)(m0 + r_) * 1024 + (kt) * 64 + c_ * 8, \
               &As[bb][rb_ * 64]); }
#define QKV_STAGE_B(bb, kt, i) { \
        int rb_ = wave * 16 + (i) * 8; int r_ = rb_ + srow; \
        int c_ = schk ^ (r_ & 7); \
        glds16(Wb + (size_t)(n0 + r_) * 1024 + (kt) * 64 + c_ * 8, \
               &Bs[bb][rb_ * 64]); }

    #pragma unroll
    for (int i = 0; i < 4; ++i) QKV_STAGE_A(0, 0, i);
    #pragma unroll
    for (int i = 0; i < 2; ++i) QKV_STAGE_B(0, 0, i);
    #pragma unroll
    for (int i = 0; i < 4; ++i) QKV_STAGE_A(1, 1, i);
    #pragma unroll
    for (int i = 0; i < 2; ++i) QKV_STAGE_B(1, 1, i);
    WAITCNT_VM6();               // tile 0 landed; tile 1's 6 in flight
    BARRIER();

    for (int s = 0; s < 16; ++s) {
        const int cb  = s % 3;
        const int pb  = (s + 2) % 3;
        const int kt2 = (s + 2) & 15;        // wrap: benign restage
        const __bf16* Pa_ = vmode ? &As[cb][0] : &Bs[cb][0];
        const __bf16* Pb_ = vmode ? &Bs[cb][0] : &As[cb][0];

        #pragma unroll
        for (int p = 0; p < 2; ++p) {
            bf16x8 af[4], bfr[4];
            #pragma unroll
            for (int a = 0; a < 4; ++a)
                af[a] = *(const bf16x8*)&Pa_[(wA + a * 16 + l16) * 64 +
                                             (((p * 4 + quad) ^ (l16 & 7)) * 8)];
            #pragma unroll
            for (int bb = 0; bb < 4; ++bb)
                bfr[bb] = *(const bf16x8*)&Pb_[(wB + bb * 16 + l16) * 64 +
                                               (((p * 4 + quad) ^ (l16 & 7)) * 8)];
            QKV_STAGE_A(pb, kt2, 2 * p);
            QKV_STAGE_A(pb, kt2, 2 * p + 1);
            QKV_STAGE_B(pb, kt2, p);

            if (p == 1) WAITCNT_VM6();  // tile s+1 landed; s+2's 6 in flight
            BARRIER();

            SETPRIO(1);
            #pragma unroll
            for (int a = 0; a < 4; ++a)
                #pragma unroll
                for (int bb = 0; bb < 4; ++bb)
                    acc[a][bb] = MFMA16(af[a], bfr[bb], acc[a][bb]);
            SETPRIO(0);
            BARRIER();
        }
    }

#undef QKV_STAGE_A
#undef QKV_STAGE_B

    if (!vmode) {
        #pragma unroll
        for (int a = 0; a < 4; ++a) {
            int n = n0 + wA + a * 16 + quad * 4;
            floatx4 bv4 = *(const floatx4*)&bias[n];
            int h = n >> 6, d0 = n & 63;
            #pragma unroll
            for (int bb = 0; bb < 4; ++bb) {
                int m = m0 + wB + bb * 16 + l16;
                int bt = m >> 11, ss = m & 2047;
                bf16x4 o;
                #pragma unroll
                for (int r = 0; r < 4; ++r)
                    o[r] = (__bf16)(acc[a][bb][r] + bv4[r]);
                *(bf16x4*)&outp[((size_t)(bt * 16 + h) * 2048 + ss) * 64 + d0] = o;
            }
        }
    } else {
        #pragma unroll
        for (int a = 0; a < 4; ++a) {
            int m = m0 + wA + a * 16 + quad * 4;
            int bt = m >> 11, s0 = m & 2047;
            #pragma unroll
            for (int bb = 0; bb < 4; ++bb) {
                int n = n0 + wB + bb * 16 + l16;
                float bvv = bias[n];
                int h = n >> 6, d = n & 63;
                bf16x4 o;
                #pragma unroll
                for (int r = 0; r < 4; ++r)
                    o[r] = (__bf16)(acc[a][bb][r] + bvv);
                *(bf16x4*)&outp[((size_t)(bt * 16 + h) * 64 + d) * 2048 + s0] = o;
            }
        }
    }
}

// ---------------------------------------------------------------------------
// Attention R16: grid (64, 8); 4 waves x 64 q-rows = 256 q/block (256 thr).
// KVBLK=128 as two 64-key halves; one barrier per tile:
//   { stage(t+1): 8 glds; compute h0; compute h1; vmcnt(0); barrier }
// Per half per wave: 8 K-frag reads reused over 2 q-groups (16 S^T MFMA),
// pack 4 (qg,kg) P-frags, 8 V-frag reads reused over 2 q-groups (16 PV
// MFMA) -> 16 b128 reads per 32 MFMAs (2 MFMA/read, was 1).
// ---------------------------------------------------------------------------
__global__ __launch_bounds__(256, 2) void attn_kernel(
    const __bf16* __restrict__ Q, const __bf16* __restrict__ K,
    const __bf16* __restrict__ Vt, const float* __restrict__ mask,
    float* __restrict__ out)
{
    __shared__ __bf16 Ks[2][2][64 * 64];   // [buf][half][key][d], swizzled
    __shared__ __bf16 Vs[2][2][64 * 64];   // [buf][half][d][key], swizzled
    __shared__ float  Ms[2048];            // full mask row for this batch

    const int tid  = threadIdx.x;
    const int lane = tid & 63;
    const int wave = tid >> 6;          // 0..3
    const int l32  = lane & 31;
    const int hi   = lane >> 5;         // 0/1
    const int bh   = blockIdx.x;        // head index -> XCD = bh % 8
    const int b    = bh >> 4;
    const int h    = bh & 15;
    const int q0w  = blockIdx.y * 256 + wave * 64;

    const __bf16* Qb = Q  + (size_t)bh * 2048 * 64;
    const __bf16* Kb = K  + (size_t)bh * 2048 * 64;
    const __bf16* Vb = Vt + (size_t)bh * 64 * 2048;
    const float*  mb = mask + b * 2048;

    // staging lane geometry: per glds a wave fills 8 rows x 64 cols (1KB);
    // each wave stages 16 rows per half of K and of V.
    const int rb = wave * 16;                      // LDS row base this wave
    const int sr = rb + (lane >> 3);               // row (first 8-row block)
    const int sc = ((lane & 7) ^ (sr & 7)) * 8;    // swizzle: (sr+8)&7==sr&7

    // Q fragments (B operand of S^T), two q-groups of 32 rows:
    // lane holds Q[q=q0w+qg*32+l32][d=dk*16+hi*8+j]
    bf16x8 aq[2][4];
    #pragma unroll
    for (int qg = 0; qg < 2; ++qg)
        #pragma unroll
        for (int dk = 0; dk < 4; ++dk)
            aq[qg][dk] = *(const bf16x8*)(Qb +
                (size_t)(q0w + qg * 32 + l32) * 64 + dk * 16 + hi * 8);

    f32x16 co[2][2] = {};   // ctx[qg][dt]: rows=q (C layout), cols=dt*32+l32

    // ---- prologue: stage tile 0 (8 glds/wave) + mask (2 glds/wave) ----
    glds16(Kb + (size_t)sr * 64 + sc,              &Ks[0][0][rb * 64]);
    glds16(Kb + (size_t)(sr + 8) * 64 + sc,        &Ks[0][0][(rb + 8) * 64]);
    glds16(Kb + (size_t)(64 + sr) * 64 + sc,       &Ks[0][1][rb * 64]);
    glds16(Kb + (size_t)(64 + sr + 8) * 64 + sc,   &Ks[0][1][(rb + 8) * 64]);
    glds16(Vb + (size_t)sr * 2048 + sc,            &Vs[0][0][rb * 64]);
    glds16(Vb + (size_t)(sr + 8) * 2048 + sc,      &Vs[0][0][(rb + 8) * 64]);
    glds16(Vb + (size_t)sr * 2048 + 64 + sc,       &Vs[0][1][rb * 64]);
    glds16(Vb + (size_t)(sr + 8) * 2048 + 64 + sc, &Vs[0][1][(rb + 8) * 64]);
    // mask: 8KB = 8 glds of 1KB; wave w does chunks 2w, 2w+1.
    glds16((const __bf16*)mb + (size_t)(wave * 2) * 512 + lane * 8,
           (__bf16*)Ms + (wave * 2) * 512);
    glds16((const __bf16*)mb + (size_t)(wave * 2 + 1) * 512 + lane * 8,
           (__bf16*)Ms + (wave * 2 + 1) * 512);
    WAITCNT_VM0();
    BARRIER();

    for (int t = 0; t < 16; ++t) {
        const int kn = ((t + 1) & 15) * 128;  // wrap: final restage benign
        const int nb = (t + 1) & 1;
        const int cb = t & 1;
        // ---- stage next 128-key tile (8 glds/wave) ----
        glds16(Kb + (size_t)(kn + sr) * 64 + sc,            &Ks[nb][0][rb * 64]);
        glds16(Kb + (size_t)(kn + sr + 8) * 64 + sc,        &Ks[nb][0][(rb + 8) * 64]);
        glds16(Kb + (size_t)(kn + 64 + sr) * 64 + sc,       &Ks[nb][1][rb * 64]);
        glds16(Kb + (size_t)(kn + 64 + sr + 8) * 64 + sc,   &Ks[nb][1][(rb + 8) * 64]);
        glds16(Vb + (size_t)sr * 2048 + kn + sc,            &Vs[nb][0][rb * 64]);
        glds16(Vb + (size_t)(sr + 8) * 2048 + kn + sc,      &Vs[nb][0][(rb + 8) * 64]);
        glds16(Vb + (size_t)sr * 2048 + kn + 64 + sc,       &Vs[nb][1][rb * 64]);
        glds16(Vb + (size_t)(sr + 8) * 2048 + kn + 64 + sc, &Vs[nb][1][(rb + 8) * 64]);

        #pragma unroll
        for (int hf = 0; hf < 2; ++hf) {
            const __bf16* Kt = &Ks[cb][hf][0];
            const __bf16* Vtl = &Vs[cb][hf][0];
            const int k0 = t * 128 + hf * 64;

            // ---- phase 1: read 8 K A-frags once; 16 S^T MFMAs (2 qg) ----
            bf16x8 akf[2][4];                      // [kg][dk]
            #pragma unroll
            for (int dk = 0; dk < 4; ++dk) {
                const int c0 = ((dk * 2 + hi) ^ (l32 & 7)) * 8;
                akf[0][dk] = *(const bf16x8*)&Kt[l32 * 64 + c0];
                akf[1][dk] = *(const bf16x8*)&Kt[(32 + l32) * 64 + c0];
            }
            f32x16 st[2][2] = {};                  // [qg][kg]
            SETPRIO(1);
            #pragma unroll
            for (int dk = 0; dk < 4; ++dk)
                #pragma unroll
                for (int qg = 0; qg < 2; ++qg) {
                    st[qg][0] = MFMA32(akf[0][dk], aq[qg][dk], st[qg][0]);
                    st[qg][1] = MFMA32(akf[1][dk], aq[qg][dk], st[qg][1]);
                }
            SETPRIO(0);

            // ---- phase 2: relu^2 pack, all 4 (qg,kg) -> P A-frags ----
            bf16x8 paf0[2][2], paf1[2][2];         // [qg][kg]
            const f32x4 zero4 = {};
            #pragma unroll
            for (int qg = 0; qg < 2; ++qg)
                #pragma unroll
                for (int kg = 0; kg < 2; ++kg) {
                    unsigned W[4][2];
                    #pragma unroll
                    for (int G = 0; G < 4; ++G) {
                        f32x4 v;
                        v[0] = st[qg][kg][G * 4 + 0];
                        v[1] = st[qg][kg][G * 4 + 1];
                        v[2] = st[qg][kg][G * 4 + 2];
                        v[3] = st[qg][kg][G * 4 + 3];
                        f32x4 mk = *(const f32x4*)&Ms[k0 + kg * 32 + G * 8 + hi * 4];
                        v = v * 0.125f + mk;                      // v_pk_fma_f32
                        v = __builtin_elementwise_max(v, zero4);  // v_pk_max_f32
                        v = v * v;                                // v_pk_mul_f32
                        bf16x2 w0, w1;
                        w0[0] = (__bf16)v[0]; w0[1] = (__bf16)v[1];
                        w1[0] = (__bf16)v[2]; w1[1] = (__bf16)v[3];
                        W[G][0] = __builtin_bit_cast(unsigned, w0);
                        W[G][1] = __builtin_bit_cast(unsigned, w1);
                    }
                    // repack to K=16 A-frags: lane l<->l+32 word exchange.
                    u32x2 s00 = __builtin_amdgcn_permlane32_swap(W[0][0], W[1][0], false, false);
                    u32x2 s01 = __builtin_amdgcn_permlane32_swap(W[0][1], W[1][1], false, false);
                    u32x2 s10 = __builtin_amdgcn_permlane32_swap(W[2][0], W[3][0], false, false);
                    u32x2 s11 = __builtin_amdgcn_permlane32_swap(W[2][1], W[3][1], false, false);
                    u32x4 f0, f1;
                    f0[0] = s00[0]; f0[1] = s01[0]; f0[2] = s00[1]; f0[3] = s01[1];
                    f1[0] = s10[0]; f1[1] = s11[0]; f1[2] = s10[1]; f1[3] = s11[1];
                    paf0[qg][kg] = __builtin_bit_cast(bf16x8, f0); // keys kg*32+0..15
                    paf1[qg][kg] = __builtin_bit_cast(bf16x8, f1); // keys kg*32+16..31
                }

            // ---- phase 3: PV; 4 V-frag reads per kg, reused over 2 qg ----
            SETPRIO(1);
            #pragma unroll
            for (int kg = 0; kg < 2; ++kg) {
                bf16x8 vb0[2], vb1[2];             // [dt]
                #pragma unroll
                for (int dt = 0; dt < 2; ++dt) {
                    const int d = dt * 32 + l32;
                    const int ch0 = (kg * 4 + hi) ^ (d & 7);
                    const int ch1 = (kg * 4 + 2 + hi) ^ (d & 7);
                    vb0[dt] = *(const bf16x8*)&Vtl[d * 64 + ch0 * 8];
                    vb1[dt] = *(const bf16x8*)&Vtl[d * 64 + ch1 * 8];
                }
                #pragma unroll
                for (int qg = 0; qg < 2; ++qg)
                    #pragma unroll
                    for (int dt = 0; dt < 2; ++dt) {
                        co[qg][dt] = MFMA32(paf0[qg][kg], vb0[dt], co[qg][dt]);
                        co[qg][dt] = MFMA32(paf1[qg][kg], vb1[dt], co[qg][dt]);
                    }
            }
            SETPRIO(0);
        }

        WAITCNT_VM0();          // this iter's 8 glds (issued a full tile ago)
        BARRIER();              // buf nb fully written before anyone reads it
    }

    // Epilogue: q = q0w + qg*32 + (r&3)+8*(r>>2)+4*hi, d = dt*32 + l32.
    #pragma unroll
    for (int qg = 0; qg < 2; ++qg)
        #pragma unroll
        for (int r = 0; r < 16; ++r) {
            int q = q0w + qg * 32 + (r & 3) + 8 * (r >> 2) + 4 * hi;
            float* orow = &out[(((size_t)b * 2048 + q) * 16 + h) * 64];
            orow[l32]      = co[qg][0][r];
            orow[32 + l32] = co[qg][1][r];
        }
}

// ---------------------------------------------------------------------------
extern "C" void kernel_launch(void* const* d_in, const int* in_sizes, int n_in,
                              void* d_out, int out_size, void* d_ws, size_t ws_size,
                              hipStream_t stream) {
    const float* hidden = (const float*)d_in[0];   // [4,2048,1024]
    const float* mask   = (const float*)d_in[1];   // [4,1,1,2048]
    const float* Wq     = (const float*)d_in[2];
    const float* bq     = (const float*)d_in[3];
    const float* Wk     = (const float*)d_in[4];
    const float* bk     = (const float*)d_in[5];
    const float* Wv     = (const float*)d_in[6];
    const float* bv     = (const float*)d_in[7];
    float* out = (float*)d_out;

    __bf16* qws = (__bf16*)d_ws;                       // [64][2048][64]
    __bf16* kws = qws + (size_t)64 * 2048 * 64;        // [64][2048][64]
    __bf16* vws = kws + (size_t)64 * 2048 * 64;        // [64][64][2048]
    __bf16* Xb  = vws + (size_t)64 * 2048 * 64;        // [8192][1024]
    __bf16* Wqb = Xb  + (size_t)8192 * 1024;
    __bf16* Wkb = Wqb + (size_t)1024 * 1024;
    __bf16* Wvb = Wkb + (size_t)1024 * 1024;

    convert_kernel<<<dim3(5632), dim3(256), 0, stream>>>(hidden, Wq, Wk, Wv,
                                                         Xb, Wqb, Wkb, Wvb);
    qkv_gemm_kernel<<<dim3(24, 32), dim3(512), 0, stream>>>(Xb, Wqb, Wkb, Wvb,
                                                            bq, bk, bv,
                                                            qws, kws, vws);
    attn_kernel<<<dim3(64, 8), dim3(256), 0, stream>>>(qws, kws, vws, mask, out);
}